// Round 1
// baseline (209.734 us; speedup 1.0000x reference)
//
#include <hip/hip_runtime.h>

// SemanticCaps dynamic routing, fp32.
// B=128 batches, J=10 caps, K=1152 prev-caps, M=16 cap_dim, I=8 in_size.
// ws layout: u_hat [B][J][K][M] (m contiguous) then s0 partials [B][J][9][M].

#define B_ 128
#define J_ 10
#define K_ 1152
#define M_ 16
#define I_ 8
#define KT 128
#define NT (K_ / KT)      // 9 k-tiles
#define BSTRIDE 11        // lds_b padded row stride (gcd(11,32)=1 -> conflict-free)

// ---------------- Kernel 1: u_hat + fused iter-0 partial sums ----------------
__global__ __launch_bounds__(KT)
void uhat_kernel(const float* __restrict__ x, const float* __restrict__ Ws,
                 float* __restrict__ u_hat, float* __restrict__ s0p) {
    const int b    = blockIdx.x;     // fastest-varying: 128 consecutive blocks share Ws slice in L2
    const int tile = blockIdx.y;
    const int j    = blockIdx.z;
    const int t    = threadIdx.x;
    const int k    = tile * KT + t;

    const float4* xv = (const float4*)(x + ((size_t)b * K_ + k) * I_);
    const float4 x0 = xv[0], x1 = xv[1];

    const float4* wv = (const float4*)(Ws + ((size_t)j * K_ + k) * (M_ * I_));

    float acc[M_];
#pragma unroll
    for (int m = 0; m < M_; ++m) {
        float4 w0 = wv[2 * m], w1 = wv[2 * m + 1];
        acc[m] = w0.x * x0.x + w0.y * x0.y + w0.z * x0.z + w0.w * x0.w
               + w1.x * x1.x + w1.y * x1.y + w1.z * x1.z + w1.w * x1.w;
    }

    float4* uout = (float4*)(u_hat + (((size_t)b * J_ + j) * K_ + k) * M_);
#pragma unroll
    for (int q = 0; q < 4; ++q) {
        float4 v;
        v.x = acc[4 * q + 0]; v.y = acc[4 * q + 1];
        v.z = acc[4 * q + 2]; v.w = acc[4 * q + 3];
        uout[q] = v;
    }

    // block-reduce acc[m] over the 128 k's of this tile -> s0 partial
    __shared__ float part[2][M_];
    const int lane = t & 63, wv_id = t >> 6;
#pragma unroll
    for (int m = 0; m < M_; ++m) {
        float v = acc[m];
        for (int off = 1; off < 64; off <<= 1) v += __shfl_xor(v, off, 64);
        if (lane == 0) part[wv_id][m] = v;
    }
    __syncthreads();
    if (t < M_) {
        s0p[(((size_t)b * J_ + j) * NT + tile) * M_ + t] = part[0][t] + part[1][t];
    }
}

// ---------------- Kernel 2: routing iterations (one block per batch) ----------------
__global__ __launch_bounds__(640)
void route_kernel(const float* __restrict__ u_hat, const float* __restrict__ s0p,
                  float* __restrict__ out) {
    const int b    = blockIdx.x;
    const int tid  = threadIdx.x;
    const int wave = tid >> 6;   // == j for the main passes (10 waves)
    const int lane = tid & 63;

    __shared__ float lds_b[K_ * BSTRIDE];   // b-logits [k][j], padded
    __shared__ float v_lds[J_ * M_];
    __shared__ float s_lds[J_ * M_];

    // ---- iteration 0: c uniform = 0.1, s0 from kernel-1 partials, v0 = squash(s0)
    if (tid < J_ * M_) {
        const int j2 = tid >> 4, m = tid & 15;
        float s = 0.f;
#pragma unroll
        for (int tl = 0; tl < NT; ++tl)
            s += s0p[(((size_t)b * J_ + j2) * NT + tl) * M_ + m];
        s *= 0.1f;
        float sq = s * s;
        sq += __shfl_xor(sq, 1, 64);
        sq += __shfl_xor(sq, 2, 64);
        sq += __shfl_xor(sq, 4, 64);
        sq += __shfl_xor(sq, 8, 64);
        const float n = sqrtf(sq);
        v_lds[tid] = s * (n / (1.f + sq));
    }
    __syncthreads();

    const float4* ubase = (const float4*)(u_hat + ((size_t)b * J_ + wave) * K_ * M_);

    for (int pass = 0; pass < 2; ++pass) {
        float vj[M_];
#pragma unroll
        for (int m = 0; m < M_; ++m) vj[m] = v_lds[wave * M_ + m];

        float s_loc[M_];
#pragma unroll
        for (int m = 0; m < M_; ++m) s_loc[m] = 0.f;

        for (int kc = 0; kc < K_ / 64; ++kc) {
            const int k = kc * 64 + lane;
            const float4* up = ubase + (size_t)k * 4;
            const float4 a0 = up[0], a1 = up[1], a2 = up[2], a3 = up[3];
            const float u[M_] = { a0.x, a0.y, a0.z, a0.w,
                                  a1.x, a1.y, a1.z, a1.w,
                                  a2.x, a2.y, a2.z, a2.w,
                                  a3.x, a3.y, a3.z, a3.w };
            // b-logit update: b += u . v_prev   (pass 0 starts from b=0)
            float bd = 0.f;
#pragma unroll
            for (int m = 0; m < M_; ++m) bd += u[m] * vj[m];
            if (pass == 0) lds_b[k * BSTRIDE + wave] = bd;
            else           lds_b[k * BSTRIDE + wave] += bd;
            __syncthreads();

            // softmax over j for this k (per-k, no cross-k dependency)
            float den = 0.f;
#pragma unroll
            for (int jj = 0; jj < J_; ++jj)
                den += __expf(lds_b[k * BSTRIDE + jj]);
            const float c = __expf(lds_b[k * BSTRIDE + wave]) / den;

            // accumulate s partial, u still in registers
#pragma unroll
            for (int m = 0; m < M_; ++m) s_loc[m] += c * u[m];
        }

        // reduce s partials across the wave's 64 lanes
#pragma unroll
        for (int m = 0; m < M_; ++m) {
            float v = s_loc[m];
            for (int off = 1; off < 64; off <<= 1) v += __shfl_xor(v, off, 64);
            if (lane == 0) s_lds[wave * M_ + m] = v;
        }
        __syncthreads();

        // squash -> v (or final output)
        if (tid < J_ * M_) {
            const float s = s_lds[tid];
            float sq = s * s;
            sq += __shfl_xor(sq, 1, 64);
            sq += __shfl_xor(sq, 2, 64);
            sq += __shfl_xor(sq, 4, 64);
            sq += __shfl_xor(sq, 8, 64);
            const float n = sqrtf(sq);
            const float v = s * (n / (1.f + sq));
            if (pass == 0) v_lds[tid] = v;
            else           out[(size_t)b * (J_ * M_) + tid] = v;
        }
        __syncthreads();
    }
}

extern "C" void kernel_launch(void* const* d_in, const int* in_sizes, int n_in,
                              void* d_out, int out_size, void* d_ws, size_t ws_size,
                              hipStream_t stream) {
    const float* x  = (const float*)d_in[0];   // [128][1152][8]
    const float* Ws = (const float*)d_in[1];   // [10][1152][16][8]
    float* out   = (float*)d_out;              // [128][10][16]
    float* u_hat = (float*)d_ws;                               // 23,592,960 floats
    float* s0p   = u_hat + (size_t)B_ * J_ * K_ * M_;          // + 184,320 floats

    dim3 g1(B_, NT, J_);
    uhat_kernel<<<g1, KT, 0, stream>>>(x, Ws, u_hat, s0p);
    route_kernel<<<B_, 640, 0, stream>>>(u_hat, s0p, out);
}